// Round 1
// baseline (97.150 us; speedup 1.0000x reference)
//
#include <hip/hip_runtime.h>

namespace {

constexpr int Dd = 8, Hh = 512, Ww = 512, Bb = 2;
constexpr int PLANE = Hh * Ww;                              // 262144
constexpr size_t COORDS_SZ = (size_t)Bb * 3 * Dd * PLANE;   // 12582912

// One wave per image row; lane l holds w = 8l..8l+7 (two float4 loads per
// (plane,row)). W-halos via two scalar loads with clamped offsets (replaces
// shuffles + lane-edge selects). ALL 36 loads are issued as one batch and
// pinned with sched_barrier(0) -> single memory round-trip per wave instead
// of 9-18 serialized ones (latency-bound fix).
__global__ __launch_bounds__(256) void cqi_kernel(const float* __restrict__ x,
                                                  float* __restrict__ out) {
    const int lane = threadIdx.x & 63;
    const int gid  = (blockIdx.x << 2) | (threadIdx.x >> 6);  // row id 0..8191
    const int h  = gid & (Hh - 1);
    const int bd = gid >> 9;                                  // b*8 + d
    const int b  = bd >> 3;
    const int d  = bd & 7;

    const float* pl[3];
    pl[0] = x + (size_t)(d > 0      ? bd - 1 : bd) * PLANE;
    pl[1] = x + (size_t)bd * PLANE;
    pl[2] = x + (size_t)(d < Dd - 1 ? bd + 1 : bd) * PLANE;
    const int rw[3] = { (h > 0      ? h - 1 : 0) * Ww,
                         h * Ww,
                        (h < Hh - 1 ? h + 1 : h) * Ww };

    const int w0 = lane << 3;
    const int offL = (lane == 0)  ? 0 : -1;   // replicate at image w=0
    const int offR = (lane == 63) ? 7 : 8;    // replicate at image w=511

    // ---- batched load phase: 36 independent loads, one round trip ----
    float4 q0[9], q1[9];
    float  lh[9], rh[9];
#pragma unroll
    for (int a = 0; a < 3; ++a) {
#pragma unroll
        for (int e = 0; e < 3; ++e) {
            const int i = a * 3 + e;
            const float* p = pl[a] + rw[e] + w0;
            q0[i] = *reinterpret_cast<const float4*>(p);
            q1[i] = *reinterpret_cast<const float4*>(p + 4);
            lh[i] = p[offL];
            rh[i] = p[offR];
        }
    }
    __builtin_amdgcn_sched_barrier(0);  // keep the load batch ahead of compute

    // Column accumulators over window k=0..9 (w = w0-1 .. w0+8, clamped):
    float cr[10];   // center row/plane values            W[1][1][k]
    float cm[10];   // max over all 9 (plane,row) pairs
    float fyc[10];  // W[1][2][k] - W[1][0][k]   (dy diff, also dxy column)
    float fsc[10];  // W[2][1][k] - W[0][1][k]   (ds diff, also dxs column)
    float syy[10];  // W[1][0][k] + W[1][2][k]
    float sss[10];  // W[0][1][k] + W[2][1][k]
    float uys[10];  // W[0][0][k] - W[0][2][k] - W[2][0][k] + W[2][2][k]

#pragma unroll
    for (int a = 0; a < 3; ++a) {
#pragma unroll
        for (int e = 0; e < 3; ++e) {
            const int i = a * 3 + e;
            float w[10];
            w[0] = lh[i];
            w[1] = q0[i].x; w[2] = q0[i].y; w[3] = q0[i].z; w[4] = q0[i].w;
            w[5] = q1[i].x; w[6] = q1[i].y; w[7] = q1[i].z; w[8] = q1[i].w;
            w[9] = rh[i];
#pragma unroll
            for (int k = 0; k < 10; ++k) {
                if (a == 0 && e == 0) cm[k] = w[k];
                else                  cm[k] = fmaxf(cm[k], w[k]);
                if (a == 1 && e == 1) cr[k] = w[k];
                if (a == 1 && e == 0) { fyc[k] = w[k]; syy[k] = w[k]; }
                if (a == 1 && e == 2) { syy[k] += w[k]; fyc[k] = w[k] - fyc[k]; }
                if (a == 0 && e == 1) { fsc[k] = w[k]; sss[k] = w[k]; }
                if (a == 2 && e == 1) { sss[k] += w[k]; fsc[k] = w[k] - fsc[k]; }
                if (a == 0 && e == 0) uys[k] = w[k];
                if (a == 0 && e == 2) uys[k] -= w[k];
                if (a == 2 && e == 0) uys[k] -= w[k];
                if (a == 2 && e == 2) uys[k] += w[k];
            }
        }
    }

    float* coords = out;
    float* ymax   = out + COORDS_SZ;
    const size_t idx = (size_t)(h * Ww) + w0;
    const size_t cb  = ((size_t)(b * 3) * Dd + d) * PLANE + idx;
    const size_t yb  = (size_t)bd * PLANE + idx;
    const float df = (float)d, hf = (float)h, wf = (float)w0;

#pragma unroll
    for (int half = 0; half < 2; ++half) {
        float4 oc0, oc1, oc2, oy;
        float* oc0p = &oc0.x; float* oc1p = &oc1.x;
        float* oc2p = &oc2.x; float* oyp = &oy.x;
#pragma unroll
        for (int j = 0; j < 4; ++j) {
            const int i = half * 4 + j;
            const float c0 = cr[i + 1];

            const float fx = 0.5f * (cr[i + 2] - cr[i]);
            const float fy = 0.5f * fyc[i + 1];
            const float fs = 0.5f * fsc[i + 1];

            const float dxx = (cr[i] + cr[i + 2]) - 2.0f * c0;
            const float dyy = syy[i + 1] - 2.0f * c0;
            const float dss = sss[i + 1] - 2.0f * c0;
            const float dxy = 0.25f * (fyc[i + 2] - fyc[i]);
            const float dxs = 0.25f * (fsc[i + 2] - fsc[i]);
            const float dys = 0.25f * uys[i + 1];

            const float mx = fmaxf(fmaxf(cm[i], cm[i + 1]), cm[i + 2]);
            const bool nms = (c0 == mx);

            // adjugate first column doubles as det row
            const float A00 = dyy * dss - dys * dys;
            const float A01 = dys * dxs - dxy * dss;
            const float A02 = dxy * dys - dyy * dxs;
            const float det = dxx * A00 + dxy * A01 + dxs * A02;
            const bool solved = (det != 0.0f);

            const float A11 = dxx * dss - dxs * dxs;
            const float A12 = dxy * dxs - dxx * dys;
            const float A22 = dxx * dyy - dxy * dxy;
            const float ninv = -__builtin_amdgcn_rcpf(det);  // -(1/det), approx
            const float sx = (A00 * fx + A01 * fy + A02 * fs) * ninv;  // = -sol_x
            const float sy = (A01 * fx + A11 * fy + A12 * fs) * ninv;
            const float ss = (A02 * fx + A12 * fy + A22 * fs) * ninv;

            const bool newnms = nms && solved;
            float dxv = newnms ? sx : 0.0f;
            float dyv = newnms ? sy : 0.0f;
            float dsv = newnms ? ss : 0.0f;

            const float mabs = fmaxf(fabsf(dxv), fmaxf(fabsf(dyv), fabsf(dsv)));
            const bool keep = (mabs <= 0.7f);   // false for NaN too
            dxv = keep ? dxv : 0.0f;
            dyv = keep ? dyv : 0.0f;
            dsv = keep ? dsv : 0.0f;

            const float dyval = 0.5f * (fx * dxv + fy * dyv + fs * dsv);

            oyp[j]  = c0 + dyval + (newnms ? 10.0f : 0.0f);
            oc0p[j] = df + dsv;
            oc1p[j] = (wf + (float)i) + dyv;
            oc2p[j] = hf + dxv;
        }
        const size_t off = (size_t)(half * 4);
        *reinterpret_cast<float4*>(coords + cb + off)                          = oc0;
        *reinterpret_cast<float4*>(coords + cb + (size_t)Dd * PLANE + off)     = oc1;
        *reinterpret_cast<float4*>(coords + cb + (size_t)2 * Dd * PLANE + off) = oc2;
        *reinterpret_cast<float4*>(ymax + yb + off)                            = oy;
    }
}

} // namespace

extern "C" void kernel_launch(void* const* d_in, const int* in_sizes, int n_in,
                              void* d_out, int out_size, void* d_ws, size_t ws_size,
                              hipStream_t stream) {
    const float* x = (const float*)d_in[0];
    float* out = (float*)d_out;
    dim3 grid(Bb * Dd * Hh / 4, 1, 1);   // 2048 blocks, 1 wave per row
    dim3 block(256, 1, 1);
    hipLaunchKernelGGL(cqi_kernel, grid, block, 0, stream, x, out);
}

// Round 2
// 85.779 us; speedup vs baseline: 1.1326x; 1.1326x over previous
//
#include <hip/hip_runtime.h>

namespace {

constexpr int Dd = 8, Hh = 512, Ww = 512, Bb = 2;
constexpr int PLANE = Hh * Ww;                              // 262144
constexpr size_t COORDS_SZ = (size_t)Bb * 3 * Dd * PLANE;   // 12582912

// One wave per image row; lane l holds w = 8l..8l+7 (two float4 loads per
// (plane,row)); W-halos via cross-lane shuffle. Column-wise precompute
// (running max + difference/sum columns) cuts per-voxel VALU ~1.5x.
// __launch_bounds__(256,4): cap VGPR at 128 -> 4 waves/SIMD residency
// (occupancy halves at the 128-VGPR step; round-0 was above it).
// syy/sss/uys only ever read at window indices 1..8 -> 8-wide (saves 6 VGPR).
__global__ __launch_bounds__(256, 4) void cqi_kernel(const float* __restrict__ x,
                                                     float* __restrict__ out) {
    const int lane = threadIdx.x & 63;
    const int gid  = (blockIdx.x << 2) | (threadIdx.x >> 6);  // row id 0..8191
    const int h  = gid & (Hh - 1);
    const int bd = gid >> 9;                                  // b*8 + d
    const int b  = bd >> 3;
    const int d  = bd & 7;

    const float* pl[3];
    pl[0] = x + (size_t)(d > 0      ? bd - 1 : bd) * PLANE;
    pl[1] = x + (size_t)bd * PLANE;
    pl[2] = x + (size_t)(d < Dd - 1 ? bd + 1 : bd) * PLANE;
    const int rw[3] = { (h > 0      ? h - 1 : 0) * Ww,
                         h * Ww,
                        (h < Hh - 1 ? h + 1 : h) * Ww };

    const int w0 = lane << 3;

    // Column accumulators over window k=0..9 (w = w0-1 .. w0+8, clamped):
    float cr[10];   // center row/plane values            W[1][1][k]
    float cm[10];   // max over all 9 (plane,row) pairs
    float fyc[10];  // W[1][2][k] - W[1][0][k]   (dy diff, also dxy column)
    float fsc[10];  // W[2][1][k] - W[0][1][k]   (ds diff, also dxs column)
    float syy[8];   // W[1][0][k] + W[1][2][k],  k=1..8 stored at [k-1]
    float sss[8];   // W[0][1][k] + W[2][1][k],  k=1..8
    float uys[8];   // W[0][0]-W[0][2]-W[2][0]+W[2][2], k=1..8

#pragma unroll
    for (int a = 0; a < 3; ++a) {
#pragma unroll
        for (int e = 0; e < 3; ++e) {
            const float* p = pl[a] + rw[e] + w0;
            const float4 q0 = *reinterpret_cast<const float4*>(p);
            const float4 q1 = *reinterpret_cast<const float4*>(p + 4);
            const float lh = __shfl_up(q1.w, 1);
            const float rh = __shfl_down(q0.x, 1);
            float w[10];
            w[0] = (lane == 0)  ? q0.x : lh;   // replicate at image w=0
            w[1] = q0.x; w[2] = q0.y; w[3] = q0.z; w[4] = q0.w;
            w[5] = q1.x; w[6] = q1.y; w[7] = q1.z; w[8] = q1.w;
            w[9] = (lane == 63) ? q1.w : rh;   // replicate at image w=511
#pragma unroll
            for (int k = 0; k < 10; ++k) {
                if (a == 0 && e == 0) cm[k] = w[k];
                else                  cm[k] = fmaxf(cm[k], w[k]);
                if (a == 1 && e == 1) cr[k] = w[k];
                if (a == 1 && e == 0) fyc[k] = w[k];
                if (a == 1 && e == 2) fyc[k] = w[k] - fyc[k];
                if (a == 0 && e == 1) fsc[k] = w[k];
                if (a == 2 && e == 1) fsc[k] = w[k] - fsc[k];
                if (k >= 1 && k <= 8) {
                    const int m = k - 1;
                    if (a == 1 && e == 0) syy[m] = w[k];
                    if (a == 1 && e == 2) syy[m] += w[k];
                    if (a == 0 && e == 1) sss[m] = w[k];
                    if (a == 2 && e == 1) sss[m] += w[k];
                    if (a == 0 && e == 0) uys[m] = w[k];
                    if (a == 0 && e == 2) uys[m] -= w[k];
                    if (a == 2 && e == 0) uys[m] -= w[k];
                    if (a == 2 && e == 2) uys[m] += w[k];
                }
            }
        }
    }

    float* coords = out;
    float* ymax   = out + COORDS_SZ;
    const size_t idx = (size_t)(h * Ww) + w0;
    const size_t cb  = ((size_t)(b * 3) * Dd + d) * PLANE + idx;
    const size_t yb  = (size_t)bd * PLANE + idx;
    const float df = (float)d, hf = (float)h, wf = (float)w0;

#pragma unroll
    for (int half = 0; half < 2; ++half) {
        float4 oc0, oc1, oc2, oy;
        float* oc0p = &oc0.x; float* oc1p = &oc1.x;
        float* oc2p = &oc2.x; float* oyp = &oy.x;
#pragma unroll
        for (int j = 0; j < 4; ++j) {
            const int i = half * 4 + j;
            const float c0 = cr[i + 1];

            const float fx = 0.5f * (cr[i + 2] - cr[i]);
            const float fy = 0.5f * fyc[i + 1];
            const float fs = 0.5f * fsc[i + 1];

            const float dxx = (cr[i] + cr[i + 2]) - 2.0f * c0;
            const float dyy = syy[i] - 2.0f * c0;
            const float dss = sss[i] - 2.0f * c0;
            const float dxy = 0.25f * (fyc[i + 2] - fyc[i]);
            const float dxs = 0.25f * (fsc[i + 2] - fsc[i]);
            const float dys = 0.25f * uys[i];

            const float mx = fmaxf(fmaxf(cm[i], cm[i + 1]), cm[i + 2]);
            const bool nms = (c0 == mx);

            // adjugate first column doubles as det row
            const float A00 = dyy * dss - dys * dys;
            const float A01 = dys * dxs - dxy * dss;
            const float A02 = dxy * dys - dyy * dxs;
            const float det = dxx * A00 + dxy * A01 + dxs * A02;
            const bool solved = (det != 0.0f);

            const float A11 = dxx * dss - dxs * dxs;
            const float A12 = dxy * dxs - dxx * dys;
            const float A22 = dxx * dyy - dxy * dxy;
            const float ninv = -__builtin_amdgcn_rcpf(det);  // -(1/det), approx
            const float sx = (A00 * fx + A01 * fy + A02 * fs) * ninv;  // = -sol_x
            const float sy = (A01 * fx + A11 * fy + A12 * fs) * ninv;
            const float ss = (A02 * fx + A12 * fy + A22 * fs) * ninv;

            const bool newnms = nms && solved;
            float dxv = newnms ? sx : 0.0f;
            float dyv = newnms ? sy : 0.0f;
            float dsv = newnms ? ss : 0.0f;

            const float mabs = fmaxf(fabsf(dxv), fmaxf(fabsf(dyv), fabsf(dsv)));
            const bool keep = (mabs <= 0.7f);   // false for NaN too
            dxv = keep ? dxv : 0.0f;
            dyv = keep ? dyv : 0.0f;
            dsv = keep ? dsv : 0.0f;

            const float dyval = 0.5f * (fx * dxv + fy * dyv + fs * dsv);

            oyp[j]  = c0 + dyval + (newnms ? 10.0f : 0.0f);
            oc0p[j] = df + dsv;
            oc1p[j] = (wf + (float)i) + dyv;
            oc2p[j] = hf + dxv;
        }
        const size_t off = (size_t)(half * 4);
        *reinterpret_cast<float4*>(coords + cb + off)                          = oc0;
        *reinterpret_cast<float4*>(coords + cb + (size_t)Dd * PLANE + off)     = oc1;
        *reinterpret_cast<float4*>(coords + cb + (size_t)2 * Dd * PLANE + off) = oc2;
        *reinterpret_cast<float4*>(ymax + yb + off)                            = oy;
    }
}

} // namespace

extern "C" void kernel_launch(void* const* d_in, const int* in_sizes, int n_in,
                              void* d_out, int out_size, void* d_ws, size_t ws_size,
                              hipStream_t stream) {
    const float* x = (const float*)d_in[0];
    float* out = (float*)d_out;
    dim3 grid(Bb * Dd * Hh / 4, 1, 1);   // 2048 blocks, 1 wave per row
    dim3 block(256, 1, 1);
    hipLaunchKernelGGL(cqi_kernel, grid, block, 0, stream, x, out);
}